// Round 20
// baseline (261.068 us; speedup 1.0000x reference)
//
#include <hip/hip_runtime.h>
#include <hip/hip_bf16.h>
#include <cstdint>

#define NLOC 128        // nodes per graph
#define NGRAPH 128      // bs*T
#define NNODE 16384     // total nodes
#define EBASE 2048      // base edges per graph

typedef _Float16 half2v __attribute__((ext_vector_type(2)));
typedef _Float16 f16x8 __attribute__((ext_vector_type(8)));
typedef float f32x4 __attribute__((ext_vector_type(4)));

__device__ __forceinline__ float sigf(float x) { return 1.f / (1.f + __expf(-x)); }
__device__ __forceinline__ float tanhfast(float x) {
    float e = __expf(2.f * x);
    return 1.f - 2.f / (e + 1.f);
}
__device__ __forceinline__ uint32_t packh2(float a, float b) {
    half2v v;
    v.x = (_Float16)a; v.y = (_Float16)b;
    return __builtin_bit_cast(uint32_t, v);
}
__device__ __forceinline__ float dot2(uint32_t w, uint32_t h, float acc) {
#if __has_builtin(__builtin_amdgcn_fdot2)
    return __builtin_amdgcn_fdot2(__builtin_bit_cast(half2v, w),
                                  __builtin_bit_cast(half2v, h), acc, false);
#else
    half2v wv = __builtin_bit_cast(half2v, w);
    half2v hv = __builtin_bit_cast(half2v, h);
    return acc + (float)wv.x * (float)hv.x + (float)wv.y * (float)hv.y;
#endif
}

// ---------------- prep: adjacency + LSTM weight pack + per-graph flag reset ---------------
__global__ __launch_bounds__(256) void prep_kernel(const int* __restrict__ ei,
                                                   float* __restrict__ Adj,
                                                   const float* __restrict__ Whh_f,
                                                   const float* __restrict__ Whh_b,
                                                   uint32_t* __restrict__ wreg,
                                                   uint32_t* __restrict__ wtail,
                                                   int* __restrict__ gflag1,
                                                   int* __restrict__ gflag2) {
    int b = blockIdx.x, tid = threadIdx.x;
    if (b < 128) {
        __shared__ int rowA[NLOC];
        int v = b;
        if (tid == 0) { gflag1[v] = 0; gflag2[v] = 0; }   // replay-safe flag reset
        if (tid < NLOC) rowA[tid] = 0;
        __syncthreads();
        const int* srcs = ei;
        const int* dsts = ei + EBASE;
        int e0 = tid * 8;
#pragma unroll
        for (int k = 0; k < 8; ++k)
            if (dsts[e0 + k] == v) atomicAdd(&rowA[srcs[e0 + k]], 1);
        __syncthreads();
        if (tid < NLOC) Adj[v * NLOC + tid] = (float)rowA[tid] + (tid == v ? 1.f : 0.f);
    } else {
        int gid = (b - 128) * 256 + tid;       // 0..2047
        int dir = gid >> 10, row = gid & 1023;
        const float* src = (dir ? Whh_b : Whh_f) + (size_t)row * 256;
        uint4* wr4 = (uint4*)wreg;
#pragma unroll
        for (int i = 0; i < 24; ++i) {
            uint4 v;
            v.x = packh2(src[i * 8 + 0], src[i * 8 + 1]);
            v.y = packh2(src[i * 8 + 2], src[i * 8 + 3]);
            v.z = packh2(src[i * 8 + 4], src[i * 8 + 5]);
            v.w = packh2(src[i * 8 + 6], src[i * 8 + 7]);
            wr4[(size_t)(dir * 24 + i) * 1024 + row] = v;
        }
        uint4* wt4 = (uint4*)wtail;
#pragma unroll
        for (int ku = 0; ku < 8; ++ku) {
            const float* s8 = src + 192 + ku * 8;
            uint4 v;
            v.x = packh2(s8[0], s8[1]);
            v.y = packh2(s8[2], s8[3]);
            v.z = packh2(s8[4], s8[5]);
            v.w = packh2(s8[6], s8[7]);
            wt4[(size_t)(dir * 8 + ku) * 1024 + row] = v;
        }
    }
}

// ---------------- fused GAT layer body (R16/R19-verified logic, raw passed in) ------------
template <int K, int NL, int NF, bool POOLX>
__device__ void fl_body(int g, int foff,
                        const float* __restrict__ A,
                        const float* __restrict__ Wg,
                        const float* __restrict__ a_s,
                        const float* __restrict__ a_d,
                        const float* __restrict__ Adj,
                        const float* __restrict__ bias,
                        const float* __restrict__ Wih_f, const float* __restrict__ bif, const float* __restrict__ bhf,
                        const float* __restrict__ Wih_b, const float* __restrict__ bib, const float* __restrict__ bhb,
                        float* __restrict__ outG,
                        char* raw, float* as_l, float* ad_l, float* den_l,
                        float (*as_part)[128], float (*ad_part)[128],
                        float (*psum)[64], float* emb) {
    constexpr int HL = NL / 64;
    constexpr int NT = NL / 64;
    constexpr int WPH = 4 / HL;
    constexpr int NLSH = (NL == 128) ? 7 : 6;
    constexpr int LDA = K + 4;
    constexpr int LDB = 68;
    constexpr int LDH = 136;
    constexpr int ASB = 128 * LDA * 2;
    constexpr int HTB = NL * LDH * 2;
    constexpr int R1 = (ASB > HTB) ? ASB : HTB;
    _Float16* As = (_Float16*)raw;
    _Float16* Ht = (_Float16*)raw;                // aliases As (As dead first)
    _Float16* Bs = (_Float16*)(raw + R1);
    _Float16* Wt = (_Float16*)(raw + R1);         // aliases Bs

    int tid = threadIdx.x;
    int lane = tid & 63, w = tid >> 6;
    int wm = w >> 2, wn = w & 3;
    int col = lane & 15, kg = lane >> 4;
    size_t base = (size_t)g * 128;

    float asc[NT], adc[NT];
#pragma unroll
    for (int nt = 0; nt < NT; ++nt) {
        int f = foff + (wn * NT + nt) * 16 + col;
        asc[nt] = a_s[f];
        adc[nt] = a_d[f];
    }
    // ---- stage A (f32 -> f16)
    {
        const float* src = A + base * K;
        for (int i = tid; i < 128 * K / 2; i += 512) {
            int m = (2 * i) / K, k = (2 * i) % K;
            float2 v = *(const float2*)(src + (size_t)m * K + k);
            *(uint32_t*)&As[m * LDA + k] = packh2(v.x, v.y);
        }
    }
    // ---- GEMM
    f32x4 acc[4][NT];
#pragma unroll
    for (int mt = 0; mt < 4; ++mt)
#pragma unroll
        for (int nt = 0; nt < NT; ++nt) acc[mt][nt] = (f32x4){0.f, 0.f, 0.f, 0.f};
#pragma unroll 1
    for (int kc = 0; kc < K / 64; ++kc) {
        __syncthreads();
        for (int j = tid; j < NL * 32; j += 512) {
            int n = j & (NL - 1), kk = j >> NLSH;
            int k = kc * 64 + 2 * kk;
            float w0 = Wg[(size_t)k * NF + foff + n];
            float w1 = Wg[(size_t)(k + 1) * NF + foff + n];
            *(uint32_t*)&Bs[n * LDB + 2 * kk] = packh2(w0, w1);
        }
        __syncthreads();
        uint4 bf[NT][2];
#pragma unroll
        for (int nt = 0; nt < NT; ++nt) {
            int nb = (wn * NT + nt) * 16 + col;
            bf[nt][0] = *(const uint4*)&Bs[nb * LDB + kg * 8];
            bf[nt][1] = *(const uint4*)&Bs[nb * LDB + 32 + kg * 8];
        }
#pragma unroll
        for (int mt = 0; mt < 4; ++mt) {
            int mrow = wm * 64 + mt * 16 + col;
            uint4 a0 = *(const uint4*)&As[mrow * LDA + kc * 64 + kg * 8];
            uint4 a1 = *(const uint4*)&As[mrow * LDA + kc * 64 + 32 + kg * 8];
#pragma unroll
            for (int nt = 0; nt < NT; ++nt) {
                acc[mt][nt] = __builtin_amdgcn_mfma_f32_16x16x32_f16(
                    __builtin_bit_cast(f16x8, a0), __builtin_bit_cast(f16x8, bf[nt][0]),
                    acc[mt][nt], 0, 0, 0);
                acc[mt][nt] = __builtin_amdgcn_mfma_f32_16x16x32_f16(
                    __builtin_bit_cast(f16x8, a1), __builtin_bit_cast(f16x8, bf[nt][1]),
                    acc[mt][nt], 0, 0, 0);
            }
        }
    }
    __syncthreads();    // all As/Bs reads done -> Ht/Wt may overwrite
    // ---- phase 2: Ht + attention dot partials
#pragma unroll
    for (int mt = 0; mt < 4; ++mt) {
        int mb = wm * 64 + mt * 16;
        float pas[4] = {0.f, 0.f, 0.f, 0.f}, pdd[4] = {0.f, 0.f, 0.f, 0.f};
#pragma unroll
        for (int nt = 0; nt < NT; ++nt) {
#pragma unroll
            for (int r = 0; r < 4; ++r) {
                float hv = acc[mt][nt][r];
                pas[r] += hv * asc[nt];
                pdd[r] += hv * adc[nt];
            }
            int f = (wn * NT + nt) * 16 + col;
            *(uint32_t*)&Ht[f * LDH + mb + kg * 4] = packh2(acc[mt][nt][0], acc[mt][nt][1]);
            *(uint32_t*)&Ht[f * LDH + mb + kg * 4 + 2] = packh2(acc[mt][nt][2], acc[mt][nt][3]);
        }
#pragma unroll
        for (int off = 1; off < 16; off <<= 1)
#pragma unroll
            for (int r = 0; r < 4; ++r) {
                pas[r] += __shfl_xor(pas[r], off, 64);
                pdd[r] += __shfl_xor(pdd[r], off, 64);
            }
        if (col == 0) {
#pragma unroll
            for (int r = 0; r < 4; ++r) {
                int m = mb + kg * 4 + r;
                as_part[wn][m] = pas[r];
                ad_part[wn][m] = pdd[r];
            }
        }
    }
    __syncthreads();
    if (tid < 128) {
#pragma unroll
        for (int hl = 0; hl < HL; ++hl) {
            float sa = 0.f, sd = 0.f;
#pragma unroll
            for (int q = 0; q < WPH; ++q) {
                sa += as_part[hl * WPH + q][tid];
                sd += ad_part[hl * WPH + q][tid];
            }
            as_l[tid * HL + hl] = sa;
            ad_l[tid * HL + hl] = sd;
        }
    }
    __syncthreads();
    // ---- phase 3: aggregation per local head
    for (int h = 0; h < HL; ++h) {
        {
            int v = tid >> 2, ub = (tid & 3) * 32;
            float advv = ad_l[v * HL + h];
            const float* arow = Adj + (size_t)v * 128 + ub;
            float dsum = 0.f;
#pragma unroll
            for (int j = 0; j < 16; ++j) {
                float a0 = arow[2 * j], a1 = arow[2 * j + 1];
                float e0 = as_l[(ub + 2 * j) * HL + h] + advv;
                float e1 = as_l[(ub + 2 * j + 1) * HL + h] + advv;
                e0 = (e0 > 0.f) ? e0 : 0.2f * e0;
                e1 = (e1 > 0.f) ? e1 : 0.2f * e1;
                float w0 = a0 * __expf(e0);
                float w1 = a1 * __expf(e1);
                dsum += w0 + w1;
                *(uint32_t*)&Wt[v * LDH + ub + 2 * j] = packh2(w0, w1);
            }
            dsum += __shfl_xor(dsum, 1, 64);
            dsum += __shfl_xor(dsum, 2, 64);
            if ((tid & 3) == 0) den_l[v] = dsum;
        }
        __syncthreads();
        {
            int vt = w;
            f16x8 af[4];
#pragma unroll
            for (int kt = 0; kt < 4; ++kt) {
                uint4 au = *(const uint4*)&Wt[(vt * 16 + col) * LDH + kt * 32 + kg * 8];
                af[kt] = __builtin_bit_cast(f16x8, au);
            }
            float dn[4];
#pragma unroll
            for (int r = 0; r < 4; ++r) dn[r] = den_l[vt * 16 + kg * 4 + r] + 1e-16f;
#pragma unroll
            for (int ft = 0; ft < 4; ++ft) {
                int f = h * 64 + ft * 16 + col;
                f32x4 oacc = {0.f, 0.f, 0.f, 0.f};
#pragma unroll
                for (int kt = 0; kt < 4; ++kt) {
                    uint4 bu = *(const uint4*)&Ht[f * LDH + kt * 32 + kg * 8];
                    oacc = __builtin_amdgcn_mfma_f32_16x16x32_f16(
                        af[kt], __builtin_bit_cast(f16x8, bu), oacc, 0, 0, 0);
                }
                float bv = bias[foff + f];
                if constexpr (!POOLX) {
#pragma unroll
                    for (int r = 0; r < 4; ++r) {
                        int v = vt * 16 + kg * 4 + r;
                        float o = oacc[r] / dn[r] + bv;
                        outG[(size_t)(base + v) * NF + foff + f] = fmaxf(o, 0.f);
                    }
                } else {
                    float ps = 0.f;
#pragma unroll
                    for (int r = 0; r < 4; ++r) ps += fmaxf(oacc[r] / dn[r] + bv, 0.f);
                    ps += __shfl_xor(ps, 16, 64);
                    ps += __shfl_xor(ps, 32, 64);
                    if (kg == 0) psum[w][f] = ps;
                }
            }
        }
        __syncthreads();
    }
    if constexpr (POOLX) {
        if (tid < 64) {
            float s = 0.f;
#pragma unroll
            for (int q = 0; q < 8; ++q) s += psum[q][tid];
            emb[tid] = s;
        }
        __syncthreads();
        int rrow = (g & 31) * 4 + (g >> 5);
        for (int dir = 0; dir < 2; ++dir) {
            const float* W = dir ? Wih_b : Wih_f;
            const float* bi = dir ? bib : bif;
            const float* bh = dir ? bhb : bhf;
            for (int o = tid; o < 1024; o += 512) {
                const float* wr = W + (size_t)o * 64;
                float s = bi[o] + bh[o];
#pragma unroll
                for (int k = 0; k < 64; k += 4) {
                    float4 wv = *(const float4*)(wr + k);
                    s += emb[k] * wv.x + emb[k + 1] * wv.y + emb[k + 2] * wv.z + emb[k + 3] * wv.w;
                }
                outG[dir * 131072 + rrow * 1024 + o] = s;
            }
        }
    }
}

// ---------------- GAT megakernel: 3 layers pipelined via per-graph flags -------------------
// 256 blocks x 512 thr, 1 block/CU (LDS ~111KB) -> ALL co-resident -> spin-wait is safe.
// fl2(g) needs only fl1(g,0)+(g,1) (graph g's rows): producer __threadfence + atomicAdd;
// consumer acquire-spins >= 2 (R1-proven device-scope pattern). Replaces 2 dispatch gaps.
struct MegaArgs {
    const float* x;
    const float* W1; const float* as1; const float* ad1; const float* b1;
    const float* W2; const float* as2; const float* ad2; const float* b2;
    const float* W3; const float* as3; const float* ad3; const float* b3;
    const float* Wih_f; const float* bif; const float* bhf;
    const float* Wih_b; const float* bib; const float* bhb;
    const float* Adj;
    float* buf1; float* buf2; float* xp;
    int* gflag1; int* gflag2;
};

__global__ __launch_bounds__(512) void gat_mega(MegaArgs a) {
    __shared__ __align__(16) char raw[101376];
    __shared__ float as_l[256], ad_l[256], den_l[128];
    __shared__ float as_part[4][128], ad_part[4][128];
    __shared__ float psum[8][64], emb[64];
    int b = blockIdx.x, tid = threadIdx.x;
    int g = b & 127, hb = b >> 7;
    // ---- layer 1
    fl_body<64, 128, 256, false>(g, hb * 128, a.x, a.W1, a.as1, a.ad1, a.Adj, a.b1,
        a.Wih_f, a.bif, a.bhf, a.Wih_b, a.bib, a.bhb, a.buf1,
        raw, as_l, ad_l, den_l, as_part, ad_part, psum, emb);
    // signal fl1(g,hb) done; wait for both halves of graph g
    __threadfence();
    __syncthreads();
    if (tid == 0) {
        atomicAdd(&a.gflag1[g], 1);
        while (__hip_atomic_load(&a.gflag1[g], __ATOMIC_ACQUIRE, __HIP_MEMORY_SCOPE_AGENT) < 2)
            __builtin_amdgcn_s_sleep(1);
    }
    __syncthreads();
    // ---- layer 2
    fl_body<256, 128, 256, false>(g, hb * 128, a.buf1, a.W2, a.as2, a.ad2, a.Adj, a.b2,
        a.Wih_f, a.bif, a.bhf, a.Wih_b, a.bib, a.bhb, a.buf2,
        raw, as_l, ad_l, den_l, as_part, ad_part, psum, emb);
    __threadfence();
    __syncthreads();
    if (tid == 0) {
        atomicAdd(&a.gflag2[g], 1);
        if (hb == 0)
            while (__hip_atomic_load(&a.gflag2[g], __ATOMIC_ACQUIRE, __HIP_MEMORY_SCOPE_AGENT) < 2)
                __builtin_amdgcn_s_sleep(1);
    }
    if (hb != 0) return;                     // half-1 blocks exit
    __syncthreads();
    // ---- layer 3 + pool + xpart (128 blocks)
    fl_body<256, 64, 64, true>(g, 0, a.buf2, a.W3, a.as3, a.ad3, a.Adj, a.b3,
        a.Wih_f, a.bif, a.bhf, a.Wih_b, a.bib, a.bhb, a.xp,
        raw, as_l, ad_l, den_l, as_part, ad_part, psum, emb);
}

// ---------------- BiLSTM recurrent v7 (pinned floor ~75us; control) -----------------------
__global__ __launch_bounds__(1024, 1) void lstm_kernel(const float* __restrict__ xp,
                                                       const uint32_t* __restrict__ wreg,
                                                       const uint32_t* __restrict__ wtail,
                                                       float* __restrict__ hT) {
    int blk = blockIdx.x;
    int dir = blk >> 2, batch = blk & 3;
    int t = threadIdx.x;
    uint32_t wa[96];
    {
        const uint4* ra = (const uint4*)wreg + (size_t)dir * 24 * 1024;
#pragma unroll
        for (int i = 0; i < 24; ++i) {
            uint4 v = ra[i * 1024 + t];
            wa[i * 4 + 0] = v.x; wa[i * 4 + 1] = v.y; wa[i * 4 + 2] = v.z; wa[i * 4 + 3] = v.w;
        }
    }
    __shared__ __align__(16) uint4 wlds[8 * 1024];
    __shared__ __align__(16) uint32_t h_pk[128];
    __shared__ float gv[1024];
    {
        const uint4* tsrc = (const uint4*)wtail + (size_t)dir * 8 * 1024;
        for (int i = t; i < 8 * 1024; i += 1024) wlds[i] = tsrc[i];
    }
    if (t < 128) h_pk[t] = 0;
    __syncthreads();
    float creg = 0.f;
    const float* xpb = xp + dir * 131072 + batch * 1024;
#pragma unroll 1
    for (int step = 0; step < 32; ++step) {
        int teff = dir ? (31 - step) : step;
        float xa = xpb[teff * 4096 + t];
        float acc = 0.f;
#pragma unroll
        for (int q = 0; q < 24; ++q) {
            uint4 hq = *(const uint4*)&h_pk[q * 4];
            acc = dot2(wa[q * 4 + 0], hq.x, acc);
            acc = dot2(wa[q * 4 + 1], hq.y, acc);
            acc = dot2(wa[q * 4 + 2], hq.z, acc);
            acc = dot2(wa[q * 4 + 3], hq.w, acc);
        }
#pragma unroll
        for (int ku = 0; ku < 8; ++ku) {
            uint4 hq = *(const uint4*)&h_pk[96 + ku * 4];
            uint4 qa = wlds[ku * 1024 + t];
            acc = dot2(qa.x, hq.x, acc); acc = dot2(qa.y, hq.y, acc);
            acc = dot2(qa.z, hq.z, acc); acc = dot2(qa.w, hq.w, acc);
        }
        gv[t] = acc + xa;
        __syncthreads();
        if (t < 256) {
            float iv = gv[t], fv = gv[t + 256], gg = gv[t + 512], ov = gv[t + 768];
            creg = sigf(fv) * creg + sigf(iv) * tanhfast(gg);
            float hv = sigf(ov) * tanhfast(creg);
            if (step == 31) hT[(size_t)(dir * 4 + batch) * 256 + t] = hv;
            float hnext = __shfl_down(hv, 1, 64);
            if ((t & 1) == 0) h_pk[t >> 1] = packh2(hv, hnext);
        }
        __syncthreads();
    }
}

// ---------------- heads v2 (R16-verified): 129 blocks, 8 threads/output -------------------
__global__ __launch_bounds__(256) void heads_kernel(const float* __restrict__ hT,
                                                    const float* __restrict__ Wmu, const float* __restrict__ bmu,
                                                    const float* __restrict__ Wlv, const float* __restrict__ blv,
                                                    const float* __restrict__ Wpi, const float* __restrict__ bpi,
                                                    float* __restrict__ out) {
    __shared__ __align__(16) float feat[4][512];
    int tid = threadIdx.x;
    for (int i = tid; i < 2048; i += 256) {
        int b = i >> 9, j = i & 511;
        int d = j >> 8, jj = j & 255;
        feat[b][j] = hT[(size_t)(d * 4 + b) * 256 + jj];
    }
    __syncthreads();
    int o = blockIdx.x * 32 + (tid >> 3);
    int kp = tid & 7;
    if (o >= 4128) return;
    const float* Wr;
    float bv;
    int kind, m;
    if (o < 2048) { Wr = Wmu + (size_t)o * 512; bv = bmu[o]; kind = 0; m = o; }
    else if (o < 4096) { m = o - 2048; Wr = Wlv + (size_t)m * 512; bv = blv[m]; kind = 1; }
    else { m = o - 4096; Wr = Wpi + (size_t)m * 512; bv = bpi[m]; kind = 2; }
    float s0 = 0.f, s1 = 0.f, s2 = 0.f, s3 = 0.f;
    int k0 = kp * 64;
#pragma unroll
    for (int j = 0; j < 16; ++j) {
        int k = k0 + j * 4;
        float4 wv = *(const float4*)(Wr + k);
        s0 += feat[0][k] * wv.x + feat[0][k + 1] * wv.y + feat[0][k + 2] * wv.z + feat[0][k + 3] * wv.w;
        s1 += feat[1][k] * wv.x + feat[1][k + 1] * wv.y + feat[1][k + 2] * wv.z + feat[1][k + 3] * wv.w;
        s2 += feat[2][k] * wv.x + feat[2][k + 1] * wv.y + feat[2][k + 2] * wv.z + feat[2][k + 3] * wv.w;
        s3 += feat[3][k] * wv.x + feat[3][k + 1] * wv.y + feat[3][k + 2] * wv.z + feat[3][k + 3] * wv.w;
    }
#pragma unroll
    for (int off = 1; off < 8; off <<= 1) {
        s0 += __shfl_xor(s0, off, 64);
        s1 += __shfl_xor(s1, off, 64);
        s2 += __shfl_xor(s2, off, 64);
        s3 += __shfl_xor(s3, off, 64);
    }
    if (kp != 0) return;
    s0 += bv; s1 += bv; s2 += bv; s3 += bv;
    if (kind == 0) {
        out[0 * 2048 + m] = s0; out[1 * 2048 + m] = s1; out[2 * 2048 + m] = s2; out[3 * 2048 + m] = s3;
    } else if (kind == 1) {
        out[8192 + 0 * 2048 + m] = s0; out[8192 + 1 * 2048 + m] = s1;
        out[8192 + 2 * 2048 + m] = s2; out[8192 + 3 * 2048 + m] = s3;
    } else {
        out[16384 + 0 * 32 + m] = s0; out[16384 + 1 * 32 + m] = s1;
        out[16384 + 2 * 32 + m] = s2; out[16384 + 3 * 32 + m] = s3;
    }
}

extern "C" void kernel_launch(void* const* d_in, const int* in_sizes, int n_in,
                              void* d_out, int out_size, void* d_ws, size_t ws_size,
                              hipStream_t stream) {
    const float* x = (const float*)d_in[0];
    const int* ei = (const int*)d_in[1];
    const float* W1 = (const float*)d_in[2];
    const float* as1 = (const float*)d_in[3];
    const float* ad1 = (const float*)d_in[4];
    const float* b1 = (const float*)d_in[5];
    const float* W2 = (const float*)d_in[6];
    const float* as2 = (const float*)d_in[7];
    const float* ad2 = (const float*)d_in[8];
    const float* b2 = (const float*)d_in[9];
    const float* W3 = (const float*)d_in[10];
    const float* as3 = (const float*)d_in[11];
    const float* ad3 = (const float*)d_in[12];
    const float* b3 = (const float*)d_in[13];
    const float* Wih_f = (const float*)d_in[14];
    const float* Whh_f = (const float*)d_in[15];
    const float* bih_f = (const float*)d_in[16];
    const float* bhh_f = (const float*)d_in[17];
    const float* Wih_b = (const float*)d_in[18];
    const float* Whh_b = (const float*)d_in[19];
    const float* bih_b = (const float*)d_in[20];
    const float* bhh_b = (const float*)d_in[21];
    const float* Wmu = (const float*)d_in[22];
    const float* bmu = (const float*)d_in[23];
    const float* Wlv = (const float*)d_in[24];
    const float* blv = (const float*)d_in[25];
    const float* Wpi = (const float*)d_in[26];
    const float* bpi = (const float*)d_in[27];

    float* ws = (float*)d_ws;
    float* buf1 = ws;                        // [0, 4194304)
    float* buf2 = ws + 4194304;              // [4194304, 8388608)
    float* Adj = ws + 8388608;               // 16384
    float* xp = ws + 8404992;                // 262144
    float* hT = ws + 8667136;                // 2048
    uint32_t* wreg = (uint32_t*)(ws + 8669184);  // 196608 u32
    uint32_t* wtail = wreg + 196608;             // 65536 u32
    int* gflag1 = (int*)(wtail + 65536);         // 128 ints
    int* gflag2 = gflag1 + 128;                  // 128 ints
    float* out = (float*)d_out;

    // prep: adjacency + LSTM weight pack + flag reset (one dispatch)
    prep_kernel<<<136, 256, 0, stream>>>(ei, Adj, Whh_f, Whh_b, wreg, wtail, gflag1, gflag2);

    // GAT megakernel: all 3 layers, per-graph flag pipelining
    MegaArgs ma;
    ma.x = x;
    ma.W1 = W1; ma.as1 = as1; ma.ad1 = ad1; ma.b1 = b1;
    ma.W2 = W2; ma.as2 = as2; ma.ad2 = ad2; ma.b2 = b2;
    ma.W3 = W3; ma.as3 = as3; ma.ad3 = ad3; ma.b3 = b3;
    ma.Wih_f = Wih_f; ma.bif = bih_f; ma.bhf = bhh_f;
    ma.Wih_b = Wih_b; ma.bib = bih_b; ma.bhb = bhh_b;
    ma.Adj = Adj;
    ma.buf1 = buf1; ma.buf2 = buf2; ma.xp = xp;
    ma.gflag1 = gflag1; ma.gflag2 = gflag2;
    gat_mega<<<256, 512, 0, stream>>>(ma);

    // recurrent + heads
    lstm_kernel<<<8, 1024, 0, stream>>>(xp, wreg, wtail, hT);
    heads_kernel<<<129, 256, 0, stream>>>(hT, Wmu, bmu, Wlv, blv, Wpi, bpi, out);
}

// Round 21
// 193.780 us; speedup vs baseline: 1.3472x; 1.3472x over previous
//
#include <hip/hip_runtime.h>
#include <hip/hip_bf16.h>
#include <cstdint>

#define NLOC 128        // nodes per graph
#define NGRAPH 128      // bs*T
#define NNODE 16384     // total nodes
#define EBASE 2048      // base edges per graph

typedef _Float16 half2v __attribute__((ext_vector_type(2)));
typedef _Float16 f16x8 __attribute__((ext_vector_type(8)));
typedef float f32x4 __attribute__((ext_vector_type(4)));

__device__ __forceinline__ float sigf(float x) { return 1.f / (1.f + __expf(-x)); }
__device__ __forceinline__ float tanhfast(float x) {
    float e = __expf(2.f * x);
    return 1.f - 2.f / (e + 1.f);
}
__device__ __forceinline__ uint32_t packh2(float a, float b) {
    half2v v;
    v.x = (_Float16)a; v.y = (_Float16)b;
    return __builtin_bit_cast(uint32_t, v);
}
__device__ __forceinline__ float dot2(uint32_t w, uint32_t h, float acc) {
#if __has_builtin(__builtin_amdgcn_fdot2)
    return __builtin_amdgcn_fdot2(__builtin_bit_cast(half2v, w),
                                  __builtin_bit_cast(half2v, h), acc, false);
#else
    half2v wv = __builtin_bit_cast(half2v, w);
    half2v hv = __builtin_bit_cast(half2v, h);
    return acc + (float)wv.x * (float)hv.x + (float)wv.y * (float)hv.y;
#endif
}

// ---------------- prep: adjacency + f16-transposed GAT weights + LSTM wpack ---------------
__global__ __launch_bounds__(256) void prep_kernel(const int* __restrict__ ei,
                                                   float* __restrict__ Adj,
                                                   const float* __restrict__ W1,
                                                   const float* __restrict__ W2,
                                                   const float* __restrict__ W3,
                                                   _Float16* __restrict__ W1t,
                                                   _Float16* __restrict__ W2t,
                                                   _Float16* __restrict__ W3t,
                                                   const float* __restrict__ Whh_f,
                                                   const float* __restrict__ Whh_b,
                                                   uint32_t* __restrict__ wreg,
                                                   uint32_t* __restrict__ wtail) {
    int b = blockIdx.x, tid = threadIdx.x;
    if (b < 128) {
        __shared__ int rowA[NLOC];
        int v = b;
        if (tid < NLOC) rowA[tid] = 0;
        __syncthreads();
        const int* srcs = ei;
        const int* dsts = ei + EBASE;
        int e0 = tid * 8;
#pragma unroll
        for (int k = 0; k < 8; ++k)
            if (dsts[e0 + k] == v) atomicAdd(&rowA[srcs[e0 + k]], 1);
        __syncthreads();
        if (tid < NLOC) Adj[v * NLOC + tid] = (float)rowA[tid] + (tid == v ? 1.f : 0.f);
    } else if (b < 144) {
        int i = (b - 128) * 1024 + tid * 4;
        int n = i >> 6, k = i & 63;
#pragma unroll
        for (int j = 0; j < 4; ++j) W1t[n * 64 + k + j] = (_Float16)W1[(size_t)(k + j) * 256 + n];
    } else if (b < 208) {
        int i = (b - 144) * 1024 + tid * 4;
        int n = i >> 8, k = i & 255;
#pragma unroll
        for (int j = 0; j < 4; ++j) W2t[n * 256 + k + j] = (_Float16)W2[(size_t)(k + j) * 256 + n];
    } else if (b < 224) {
        int i = (b - 208) * 1024 + tid * 4;
        int n = i >> 8, k = i & 255;
#pragma unroll
        for (int j = 0; j < 4; ++j) W3t[n * 256 + k + j] = (_Float16)W3[(size_t)(k + j) * 64 + n];
    } else {
        int gid = (b - 224) * 256 + tid;       // 0..2047
        int dir = gid >> 10, row = gid & 1023;
        const float* src = (dir ? Whh_b : Whh_f) + (size_t)row * 256;
        uint4* wr4 = (uint4*)wreg;
#pragma unroll
        for (int i = 0; i < 24; ++i) {
            uint4 v;
            v.x = packh2(src[i * 8 + 0], src[i * 8 + 1]);
            v.y = packh2(src[i * 8 + 2], src[i * 8 + 3]);
            v.z = packh2(src[i * 8 + 4], src[i * 8 + 5]);
            v.w = packh2(src[i * 8 + 6], src[i * 8 + 7]);
            wr4[(size_t)(dir * 24 + i) * 1024 + row] = v;
        }
        uint4* wt4 = (uint4*)wtail;
#pragma unroll
        for (int ku = 0; ku < 8; ++ku) {
            const float* s8 = src + 192 + ku * 8;
            uint4 v;
            v.x = packh2(s8[0], s8[1]);
            v.y = packh2(s8[2], s8[3]);
            v.z = packh2(s8[4], s8[5]);
            v.w = packh2(s8[6], s8[7]);
            wt4[(size_t)(dir * 8 + ku) * 1024 + row] = v;
        }
    }
}

// ---------------- fused GAT layer, head-split: grid (128 graphs x NF/NL) ------------------
template <int K, int NL, int NF, bool POOLX>
__global__ __launch_bounds__(512) void fl_kernel(const float* __restrict__ A,
                                                 const _Float16* __restrict__ Wg,
                                                 const float* __restrict__ a_s,
                                                 const float* __restrict__ a_d,
                                                 const float* __restrict__ Adj,
                                                 const float* __restrict__ bias,
                                                 const float* __restrict__ Wih_f, const float* __restrict__ bif, const float* __restrict__ bhf,
                                                 const float* __restrict__ Wih_b, const float* __restrict__ bib, const float* __restrict__ bhb,
                                                 float* __restrict__ outG) {
    constexpr int HL = NL / 64;
    constexpr int NT = NL / 64;
    constexpr int WPH = 4 / HL;
    constexpr int LDA = K + 4;
    constexpr int LDB = 68;
    constexpr int LDH = 136;
    constexpr int ASB = 128 * LDA * 2;
    constexpr int HTB = NL * LDH * 2;
    constexpr int R1 = (ASB > HTB) ? ASB : HTB;
    constexpr int R2 = 128 * LDH * 2;             // Wt (>= Bs = NL*LDB*2)
    __shared__ __align__(16) char raw[R1 + R2];
    _Float16* As = (_Float16*)raw;
    _Float16* Ht = (_Float16*)raw;                // aliases As (As dead first)
    _Float16* Bs = (_Float16*)(raw + R1);
    _Float16* Wt = (_Float16*)(raw + R1);         // aliases Bs
    __shared__ float as_l[128 * HL];
    __shared__ float ad_l[128 * HL];
    __shared__ float den_l[128];
    __shared__ float as_part[4][128];
    __shared__ float ad_part[4][128];
    __shared__ float psum[8][64];
    __shared__ float emb[64];

    int g = blockIdx.x, tid = threadIdx.x;
    int foff = blockIdx.y * NL;                   // global feature offset of this block
    int lane = tid & 63, w = tid >> 6;
    int wm = w >> 2, wn = w & 3;
    int col = lane & 15, kg = lane >> 4;
    size_t base = (size_t)g * 128;

    float asc[NT], adc[NT];
#pragma unroll
    for (int nt = 0; nt < NT; ++nt) {
        int f = foff + (wn * NT + nt) * 16 + col;
        asc[nt] = a_s[f];
        adc[nt] = a_d[f];
    }
    // ---- stage A (f32 -> f16)
    {
        const float* src = A + base * K;
        for (int i = tid; i < 128 * K / 2; i += 512) {
            int m = (2 * i) / K, k = (2 * i) % K;
            float2 v = *(const float2*)(src + (size_t)m * K + k);
            *(uint32_t*)&As[m * LDA + k] = packh2(v.x, v.y);
        }
    }
    // ---- GEMM
    f32x4 acc[4][NT];
#pragma unroll
    for (int mt = 0; mt < 4; ++mt)
#pragma unroll
        for (int nt = 0; nt < NT; ++nt) acc[mt][nt] = (f32x4){0.f, 0.f, 0.f, 0.f};
#pragma unroll 1
    for (int kc = 0; kc < K / 64; ++kc) {
        __syncthreads();
        for (int j = tid; j < NL * 8; j += 512) {
            int n = j >> 3, ko = (j & 7) * 8;
            *(uint4*)&Bs[n * LDB + ko] = *(const uint4*)&Wg[(size_t)(foff + n) * K + kc * 64 + ko];
        }
        __syncthreads();
        uint4 bf[NT][2];
#pragma unroll
        for (int nt = 0; nt < NT; ++nt) {
            int nb = (wn * NT + nt) * 16 + col;
            bf[nt][0] = *(const uint4*)&Bs[nb * LDB + kg * 8];
            bf[nt][1] = *(const uint4*)&Bs[nb * LDB + 32 + kg * 8];
        }
#pragma unroll
        for (int mt = 0; mt < 4; ++mt) {
            int mrow = wm * 64 + mt * 16 + col;
            uint4 a0 = *(const uint4*)&As[mrow * LDA + kc * 64 + kg * 8];
            uint4 a1 = *(const uint4*)&As[mrow * LDA + kc * 64 + 32 + kg * 8];
#pragma unroll
            for (int nt = 0; nt < NT; ++nt) {
                acc[mt][nt] = __builtin_amdgcn_mfma_f32_16x16x32_f16(
                    __builtin_bit_cast(f16x8, a0), __builtin_bit_cast(f16x8, bf[nt][0]),
                    acc[mt][nt], 0, 0, 0);
                acc[mt][nt] = __builtin_amdgcn_mfma_f32_16x16x32_f16(
                    __builtin_bit_cast(f16x8, a1), __builtin_bit_cast(f16x8, bf[nt][1]),
                    acc[mt][nt], 0, 0, 0);
            }
        }
    }
    __syncthreads();    // all As/Bs reads done -> Ht/Wt may overwrite
    // ---- phase 2: Ht (f16 transposed, local f) + attention dot partials
#pragma unroll
    for (int mt = 0; mt < 4; ++mt) {
        int mb = wm * 64 + mt * 16;
        float pas[4] = {0.f, 0.f, 0.f, 0.f}, pdd[4] = {0.f, 0.f, 0.f, 0.f};
#pragma unroll
        for (int nt = 0; nt < NT; ++nt) {
#pragma unroll
            for (int r = 0; r < 4; ++r) {
                float hv = acc[mt][nt][r];
                pas[r] += hv * asc[nt];
                pdd[r] += hv * adc[nt];
            }
            int f = (wn * NT + nt) * 16 + col;
            *(uint32_t*)&Ht[f * LDH + mb + kg * 4] = packh2(acc[mt][nt][0], acc[mt][nt][1]);
            *(uint32_t*)&Ht[f * LDH + mb + kg * 4 + 2] = packh2(acc[mt][nt][2], acc[mt][nt][3]);
        }
#pragma unroll
        for (int off = 1; off < 16; off <<= 1)
#pragma unroll
            for (int r = 0; r < 4; ++r) {
                pas[r] += __shfl_xor(pas[r], off, 64);
                pdd[r] += __shfl_xor(pdd[r], off, 64);
            }
        if (col == 0) {
#pragma unroll
            for (int r = 0; r < 4; ++r) {
                int m = mb + kg * 4 + r;
                as_part[wn][m] = pas[r];
                ad_part[wn][m] = pdd[r];
            }
        }
    }
    __syncthreads();
    if (tid < 128) {
#pragma unroll
        for (int hl = 0; hl < HL; ++hl) {
            float sa = 0.f, sd = 0.f;
#pragma unroll
            for (int q = 0; q < WPH; ++q) {
                sa += as_part[hl * WPH + q][tid];
                sd += ad_part[hl * WPH + q][tid];
            }
            as_l[tid * HL + hl] = sa;
            ad_l[tid * HL + hl] = sd;
        }
    }
    __syncthreads();
    // ---- phase 3: aggregation per local head
    for (int h = 0; h < HL; ++h) {
        {
            int v = tid >> 2, ub = (tid & 3) * 32;
            float advv = ad_l[v * HL + h];
            const float* arow = Adj + (size_t)v * 128 + ub;
            float dsum = 0.f;
#pragma unroll
            for (int j = 0; j < 16; ++j) {
                float a0 = arow[2 * j], a1 = arow[2 * j + 1];
                float e0 = as_l[(ub + 2 * j) * HL + h] + advv;
                float e1 = as_l[(ub + 2 * j + 1) * HL + h] + advv;
                e0 = (e0 > 0.f) ? e0 : 0.2f * e0;
                e1 = (e1 > 0.f) ? e1 : 0.2f * e1;
                float w0 = a0 * __expf(e0);
                float w1 = a1 * __expf(e1);
                dsum += w0 + w1;
                *(uint32_t*)&Wt[v * LDH + ub + 2 * j] = packh2(w0, w1);
            }
            dsum += __shfl_xor(dsum, 1, 64);
            dsum += __shfl_xor(dsum, 2, 64);
            if ((tid & 3) == 0) den_l[v] = dsum;
        }
        __syncthreads();
        {
            int vt = w;
            f16x8 af[4];
#pragma unroll
            for (int kt = 0; kt < 4; ++kt) {
                uint4 au = *(const uint4*)&Wt[(vt * 16 + col) * LDH + kt * 32 + kg * 8];
                af[kt] = __builtin_bit_cast(f16x8, au);
            }
            float dn[4];
#pragma unroll
            for (int r = 0; r < 4; ++r) dn[r] = den_l[vt * 16 + kg * 4 + r] + 1e-16f;
#pragma unroll
            for (int ft = 0; ft < 4; ++ft) {
                int f = h * 64 + ft * 16 + col;      // local feature
                f32x4 oacc = {0.f, 0.f, 0.f, 0.f};
#pragma unroll
                for (int kt = 0; kt < 4; ++kt) {
                    uint4 bu = *(const uint4*)&Ht[f * LDH + kt * 32 + kg * 8];
                    oacc = __builtin_amdgcn_mfma_f32_16x16x32_f16(
                        af[kt], __builtin_bit_cast(f16x8, bu), oacc, 0, 0, 0);
                }
                float bv = bias[foff + f];
                if constexpr (!POOLX) {
#pragma unroll
                    for (int r = 0; r < 4; ++r) {
                        int v = vt * 16 + kg * 4 + r;
                        float o = oacc[r] / dn[r] + bv;
                        outG[(size_t)(base + v) * NF + foff + f] = fmaxf(o, 0.f);
                    }
                } else {
                    float ps = 0.f;
#pragma unroll
                    for (int r = 0; r < 4; ++r) ps += fmaxf(oacc[r] / dn[r] + bv, 0.f);
                    ps += __shfl_xor(ps, 16, 64);
                    ps += __shfl_xor(ps, 32, 64);
                    if (kg == 0) psum[w][f] = ps;
                }
            }
        }
        __syncthreads();
    }
    if constexpr (POOLX) {
        if (tid < 64) {
            float s = 0.f;
#pragma unroll
            for (int q = 0; q < 8; ++q) s += psum[q][tid];
            emb[tid] = s;
        }
        __syncthreads();
        int rrow = (g & 31) * 4 + (g >> 5);
        for (int dir = 0; dir < 2; ++dir) {
            const float* W = dir ? Wih_b : Wih_f;
            const float* bi = dir ? bib : bif;
            const float* bh = dir ? bhb : bhf;
            for (int o = tid; o < 1024; o += 512) {
                const float* wr = W + (size_t)o * 64;
                float s = bi[o] + bh[o];
#pragma unroll
                for (int k = 0; k < 64; k += 4) {
                    float4 wv = *(const float4*)(wr + k);
                    s += emb[k] * wv.x + emb[k + 1] * wv.y + emb[k + 2] * wv.z + emb[k + 3] * wv.w;
                }
                outG[dir * 131072 + rrow * 1024 + o] = s;
            }
        }
    }
}

// ---------------- BiLSTM recurrent v7 (LDS h-distribution floor ~75us) --------------------
__global__ __launch_bounds__(1024, 1) void lstm_kernel(const float* __restrict__ xp,
                                                       const uint32_t* __restrict__ wreg,
                                                       const uint32_t* __restrict__ wtail,
                                                       float* __restrict__ hT) {
    int blk = blockIdx.x;
    int dir = blk >> 2, batch = blk & 3;
    int t = threadIdx.x;                      // gate row 0..1023
    uint32_t wa[96];
    {
        const uint4* ra = (const uint4*)wreg + (size_t)dir * 24 * 1024;
#pragma unroll
        for (int i = 0; i < 24; ++i) {
            uint4 v = ra[i * 1024 + t];
            wa[i * 4 + 0] = v.x; wa[i * 4 + 1] = v.y; wa[i * 4 + 2] = v.z; wa[i * 4 + 3] = v.w;
        }
    }
    __shared__ __align__(16) uint4 wlds[8 * 1024];   // 128 KB tail, [ku][row]
    __shared__ __align__(16) uint32_t h_pk[128];     // h as 128 half2 pairs
    __shared__ float gv[1024];
    {
        const uint4* tsrc = (const uint4*)wtail + (size_t)dir * 8 * 1024;
        for (int i = t; i < 8 * 1024; i += 1024) wlds[i] = tsrc[i];
    }
    if (t < 128) h_pk[t] = 0;
    __syncthreads();
    float creg = 0.f;
    const float* xpb = xp + dir * 131072 + batch * 1024;
#pragma unroll 1
    for (int step = 0; step < 32; ++step) {
        int teff = dir ? (31 - step) : step;
        float xa = xpb[teff * 4096 + t];
        float acc = 0.f;
#pragma unroll
        for (int q = 0; q < 24; ++q) {
            uint4 hq = *(const uint4*)&h_pk[q * 4];   // same-address broadcast b128
            acc = dot2(wa[q * 4 + 0], hq.x, acc);
            acc = dot2(wa[q * 4 + 1], hq.y, acc);
            acc = dot2(wa[q * 4 + 2], hq.z, acc);
            acc = dot2(wa[q * 4 + 3], hq.w, acc);
        }
#pragma unroll
        for (int ku = 0; ku < 8; ++ku) {
            uint4 hq = *(const uint4*)&h_pk[96 + ku * 4];  // broadcast b128
            uint4 qa = wlds[ku * 1024 + t];                // conflict-free b128
            acc = dot2(qa.x, hq.x, acc); acc = dot2(qa.y, hq.y, acc);
            acc = dot2(qa.z, hq.z, acc); acc = dot2(qa.w, hq.w, acc);
        }
        gv[t] = acc + xa;
        __syncthreads();
        if (t < 256) {
            float iv = gv[t], fv = gv[t + 256], gg = gv[t + 512], ov = gv[t + 768];
            creg = sigf(fv) * creg + sigf(iv) * tanhfast(gg);
            float hv = sigf(ov) * tanhfast(creg);
            if (step == 31) hT[(size_t)(dir * 4 + batch) * 256 + t] = hv;
            float hnext = __shfl_down(hv, 1, 64);
            if ((t & 1) == 0) h_pk[t >> 1] = packh2(hv, hnext);
        }
        __syncthreads();
    }
}

// ---------------- heads v2: 129 blocks, 8 threads per output, shfl k-reduce ---------------
__global__ __launch_bounds__(256) void heads_kernel(const float* __restrict__ hT,
                                                    const float* __restrict__ Wmu, const float* __restrict__ bmu,
                                                    const float* __restrict__ Wlv, const float* __restrict__ blv,
                                                    const float* __restrict__ Wpi, const float* __restrict__ bpi,
                                                    float* __restrict__ out) {
    __shared__ __align__(16) float feat[4][512];
    int tid = threadIdx.x;
    for (int i = tid; i < 2048; i += 256) {
        int b = i >> 9, j = i & 511;
        int d = j >> 8, jj = j & 255;
        feat[b][j] = hT[(size_t)(d * 4 + b) * 256 + jj];
    }
    __syncthreads();
    int o = blockIdx.x * 32 + (tid >> 3);     // 32 outputs/block x 8 threads each
    int kp = tid & 7;
    if (o >= 4128) return;
    const float* Wr;
    float bv;
    int kind, m;
    if (o < 2048) { Wr = Wmu + (size_t)o * 512; bv = bmu[o]; kind = 0; m = o; }
    else if (o < 4096) { m = o - 2048; Wr = Wlv + (size_t)m * 512; bv = blv[m]; kind = 1; }
    else { m = o - 4096; Wr = Wpi + (size_t)m * 512; bv = bpi[m]; kind = 2; }
    float s0 = 0.f, s1 = 0.f, s2 = 0.f, s3 = 0.f;
    int k0 = kp * 64;
#pragma unroll
    for (int j = 0; j < 16; ++j) {
        int k = k0 + j * 4;
        float4 wv = *(const float4*)(Wr + k);
        s0 += feat[0][k] * wv.x + feat[0][k + 1] * wv.y + feat[0][k + 2] * wv.z + feat[0][k + 3] * wv.w;
        s1 += feat[1][k] * wv.x + feat[1][k + 1] * wv.y + feat[1][k + 2] * wv.z + feat[1][k + 3] * wv.w;
        s2 += feat[2][k] * wv.x + feat[2][k + 1] * wv.y + feat[2][k + 2] * wv.z + feat[2][k + 3] * wv.w;
        s3 += feat[3][k] * wv.x + feat[3][k + 1] * wv.y + feat[3][k + 2] * wv.z + feat[3][k + 3] * wv.w;
    }
#pragma unroll
    for (int off = 1; off < 8; off <<= 1) {
        s0 += __shfl_xor(s0, off, 64);
        s1 += __shfl_xor(s1, off, 64);
        s2 += __shfl_xor(s2, off, 64);
        s3 += __shfl_xor(s3, off, 64);
    }
    if (kp != 0) return;
    s0 += bv; s1 += bv; s2 += bv; s3 += bv;
    if (kind == 0) {
        out[0 * 2048 + m] = s0; out[1 * 2048 + m] = s1; out[2 * 2048 + m] = s2; out[3 * 2048 + m] = s3;
    } else if (kind == 1) {
        out[8192 + 0 * 2048 + m] = s0; out[8192 + 1 * 2048 + m] = s1;
        out[8192 + 2 * 2048 + m] = s2; out[8192 + 3 * 2048 + m] = s3;
    } else {
        out[16384 + 0 * 32 + m] = s0; out[16384 + 1 * 32 + m] = s1;
        out[16384 + 2 * 32 + m] = s2; out[16384 + 3 * 32 + m] = s3;
    }
}

extern "C" void kernel_launch(void* const* d_in, const int* in_sizes, int n_in,
                              void* d_out, int out_size, void* d_ws, size_t ws_size,
                              hipStream_t stream) {
    const float* x = (const float*)d_in[0];
    const int* ei = (const int*)d_in[1];
    const float* W1 = (const float*)d_in[2];
    const float* as1 = (const float*)d_in[3];
    const float* ad1 = (const float*)d_in[4];
    const float* b1 = (const float*)d_in[5];
    const float* W2 = (const float*)d_in[6];
    const float* as2 = (const float*)d_in[7];
    const float* ad2 = (const float*)d_in[8];
    const float* b2 = (const float*)d_in[9];
    const float* W3 = (const float*)d_in[10];
    const float* as3 = (const float*)d_in[11];
    const float* ad3 = (const float*)d_in[12];
    const float* b3 = (const float*)d_in[13];
    const float* Wih_f = (const float*)d_in[14];
    const float* Whh_f = (const float*)d_in[15];
    const float* bih_f = (const float*)d_in[16];
    const float* bhh_f = (const float*)d_in[17];
    const float* Wih_b = (const float*)d_in[18];
    const float* Whh_b = (const float*)d_in[19];
    const float* bih_b = (const float*)d_in[20];
    const float* bhh_b = (const float*)d_in[21];
    const float* Wmu = (const float*)d_in[22];
    const float* bmu = (const float*)d_in[23];
    const float* Wlv = (const float*)d_in[24];
    const float* blv = (const float*)d_in[25];
    const float* Wpi = (const float*)d_in[26];
    const float* bpi = (const float*)d_in[27];

    float* ws = (float*)d_ws;
    float* buf1 = ws;                        // [0, 4194304)
    float* buf2 = ws + 4194304;              // [4194304, 8388608)
    float* Adj = ws + 8388608;               // 16384
    float* xp = ws + 8404992;                // 262144
    float* hT = ws + 8667136;                // 2048
    _Float16* W1t = (_Float16*)(ws + 8669184);   // 16384 f16
    _Float16* W2t = (_Float16*)(ws + 8677376);   // 65536 f16
    _Float16* W3t = (_Float16*)(ws + 8710144);   // 16384 f16 -> ends 8718336
    uint32_t* wreg = (uint32_t*)(ws + 8718336);  // 196608 u32 (dedicated, no overlap)
    uint32_t* wtail = wreg + 196608;             // 65536 u32
    float* out = (float*)d_out;

    // prep: adjacency + f16 GAT weights + LSTM weight pack (one dispatch)
    prep_kernel<<<232, 256, 0, stream>>>(ei, Adj, W1, W2, W3, W1t, W2t, W3t,
                                         Whh_f, Whh_b, wreg, wtail);
    // GAT layers (fused; layers 1-2 head-split over 256 blocks)
    fl_kernel<64, 128, 256, false><<<dim3(128, 2), 512, 0, stream>>>(x, W1t, as1, ad1, Adj, b1,
        Wih_f, bih_f, bhh_f, Wih_b, bih_b, bhh_b, buf1);
    fl_kernel<256, 128, 256, false><<<dim3(128, 2), 512, 0, stream>>>(buf1, W2t, as2, ad2, Adj, b2,
        Wih_f, bih_f, bhh_f, Wih_b, bih_b, bhh_b, buf2);
    fl_kernel<256, 64, 64, true><<<dim3(128, 1), 512, 0, stream>>>(buf2, W3t, as3, ad3, Adj, b3,
        Wih_f, bih_f, bhh_f, Wih_b, bih_b, bhh_b, xp);
    // recurrent + heads
    lstm_kernel<<<8, 1024, 0, stream>>>(xp, wreg, wtail, hT);
    heads_kernel<<<129, 256, 0, stream>>>(hT, Wmu, bmu, Wlv, blv, Wpi, bpi, out);
}